// Round 8
// baseline (108.532 us; speedup 1.0000x reference)
//
#include <hip/hip_runtime.h>
#include <math.h>

static constexpr int BATCH = 32;
static constexpr int SEQ   = 4096;
static constexpr int HID   = 1024;
static constexpr int PSTRIDE = HID + 8;   // ctx[1024] + m + l (+pad, keeps 16B alignment)

typedef float f32x4 __attribute__((ext_vector_type(4)));   // native vector: OK for nontemporal builtins

// -------- Pass 1: fused scores + online-softmax context partials --------
// grid = BATCH*NCHUNK blocks (NCHUNK=32 -> 1024 = exactly 4 blocks/CU, one
// balanced round; R7 lesson: grid must be a multiple of resident blocks/round).
// R8 delta: 4-row unroll -> 16 KB of loads in flight per wave (vs 8 KB),
// 4 interleaved shfl chains, one rescale check per 4 rows, float4 score store.
template<int NCHUNK>
__global__ __launch_bounds__(256, 4)
void attn_fused_pass1(const float* __restrict__ enc,
                      const float* __restrict__ dec,
                      float* __restrict__ raw_scores,   // [B,S] = weights region of d_out
                      float* __restrict__ partials)     // [B*NCHUNK][PSTRIDE]
{
    constexpr int RC  = SEQ / NCHUNK;   // rows per chunk
    constexpr int RPW = RC / 4;         // rows per wave (32 at NCHUNK=32)
    static_assert(RPW % 4 == 0, "4-row unroll");
    const int b     = blockIdx.x / NCHUNK;
    const int chunk = blockIdx.x % NCHUNK;
    const int tid   = threadIdx.x;
    const int w     = tid >> 6;
    const int lane  = tid & 63;

    __shared__ float s_dec[HID];
    __shared__ float s_ctx[4][HID];
    __shared__ float s_m[4], s_l[4];

    // stage dec[b] (4 KB) then keep this lane's 16-float fragment in registers
    ((float4*)s_dec)[tid] = ((const float4*)(dec + (size_t)b * HID))[tid];
    __syncthreads();
    const f32x4* sd = (const f32x4*)s_dec;
    const f32x4 d0 = sd[lane], d1 = sd[lane + 64], d2 = sd[lane + 128], d3 = sd[lane + 192];

    float m = -INFINITY, l = 0.f;
    f32x4 c0 = (f32x4)(0.f);
    f32x4 c1 = c0, c2 = c0, c3 = c0;

    const int row0 = chunk * RC + w * RPW;
    const f32x4* base = (const f32x4*)(enc + ((size_t)b * SEQ + row0) * HID);
    float* sout = raw_scores + (size_t)b * SEQ + row0;

    for (int r = 0; r < RPW; r += 4) {
        const f32x4* rp0 = base + (size_t)r * (HID / 4);
        const f32x4* rp1 = rp0 + (HID / 4);
        const f32x4* rp2 = rp1 + (HID / 4);
        const f32x4* rp3 = rp2 + (HID / 4);
        // 16 nontemporal 16B loads issued together: 16 KB/wave in flight
        const f32x4 e00 = __builtin_nontemporal_load(rp0 + lane);
        const f32x4 e01 = __builtin_nontemporal_load(rp0 + lane + 64);
        const f32x4 e02 = __builtin_nontemporal_load(rp0 + lane + 128);
        const f32x4 e03 = __builtin_nontemporal_load(rp0 + lane + 192);
        const f32x4 e10 = __builtin_nontemporal_load(rp1 + lane);
        const f32x4 e11 = __builtin_nontemporal_load(rp1 + lane + 64);
        const f32x4 e12 = __builtin_nontemporal_load(rp1 + lane + 128);
        const f32x4 e13 = __builtin_nontemporal_load(rp1 + lane + 192);
        const f32x4 e20 = __builtin_nontemporal_load(rp2 + lane);
        const f32x4 e21 = __builtin_nontemporal_load(rp2 + lane + 64);
        const f32x4 e22 = __builtin_nontemporal_load(rp2 + lane + 128);
        const f32x4 e23 = __builtin_nontemporal_load(rp2 + lane + 192);
        const f32x4 e30 = __builtin_nontemporal_load(rp3 + lane);
        const f32x4 e31 = __builtin_nontemporal_load(rp3 + lane + 64);
        const f32x4 e32 = __builtin_nontemporal_load(rp3 + lane + 128);
        const f32x4 e33 = __builtin_nontemporal_load(rp3 + lane + 192);

        // treed dots: per row 4 independent 4-FMA chains, then 2 adds
        float t0 = ((e00.x*d0.x + e00.y*d0.y + e00.z*d0.z + e00.w*d0.w)
                  + (e01.x*d1.x + e01.y*d1.y + e01.z*d1.z + e01.w*d1.w))
                 + ((e02.x*d2.x + e02.y*d2.y + e02.z*d2.z + e02.w*d2.w)
                  + (e03.x*d3.x + e03.y*d3.y + e03.z*d3.z + e03.w*d3.w));
        float t1 = ((e10.x*d0.x + e10.y*d0.y + e10.z*d0.z + e10.w*d0.w)
                  + (e11.x*d1.x + e11.y*d1.y + e11.z*d1.z + e11.w*d1.w))
                 + ((e12.x*d2.x + e12.y*d2.y + e12.z*d2.z + e12.w*d2.w)
                  + (e13.x*d3.x + e13.y*d3.y + e13.z*d3.z + e13.w*d3.w));
        float t2 = ((e20.x*d0.x + e20.y*d0.y + e20.z*d0.z + e20.w*d0.w)
                  + (e21.x*d1.x + e21.y*d1.y + e21.z*d1.z + e21.w*d1.w))
                 + ((e22.x*d2.x + e22.y*d2.y + e22.z*d2.z + e22.w*d2.w)
                  + (e23.x*d3.x + e23.y*d3.y + e23.z*d3.z + e23.w*d3.w));
        float t3 = ((e30.x*d0.x + e30.y*d0.y + e30.z*d0.z + e30.w*d0.w)
                  + (e31.x*d1.x + e31.y*d1.y + e31.z*d1.z + e31.w*d1.w))
                 + ((e32.x*d2.x + e32.y*d2.y + e32.z*d2.z + e32.w*d2.w)
                  + (e33.x*d3.x + e33.y*d3.y + e33.z*d3.z + e33.w*d3.w));

        // four independent 6-step reduce chains, interleaved
        #pragma unroll
        for (int off = 32; off > 0; off >>= 1) {
            t0 += __shfl_xor(t0, off, 64);
            t1 += __shfl_xor(t1, off, 64);
            t2 += __shfl_xor(t2, off, 64);
            t3 += __shfl_xor(t3, off, 64);
        }

        if (lane == 0) {
            f32x4 sc4; sc4.x = t0; sc4.y = t1; sc4.z = t2; sc4.w = t3;
            *(f32x4*)(sout + r) = sc4;       // raw scores; normalized in pass 2
        }

        const float mn = fmaxf(m, fmaxf(fmaxf(t0, t1), fmaxf(t2, t3)));
        if (mn > m) {                        // wave-uniform, rare after warm-up
            const float sc = __expf(m - mn); // m=-inf first time -> 0
            l *= sc;
            c0 *= sc; c1 *= sc; c2 *= sc; c3 *= sc;
            m = mn;
        }
        const float p0 = __expf(t0 - m);
        const float p1 = __expf(t1 - m);
        const float p2 = __expf(t2 - m);
        const float p3 = __expf(t3 - m);
        l += (p0 + p1) + (p2 + p3);
        c0 += (p0*e00 + p1*e10) + (p2*e20 + p3*e30);
        c1 += (p0*e01 + p1*e11) + (p2*e21 + p3*e31);
        c2 += (p0*e02 + p1*e12) + (p2*e22 + p3*e32);
        c3 += (p0*e03 + p1*e13) + (p2*e23 + p3*e33);
    }

    // ---- combine the 4 waves of this block ----
    if (lane == 0) { s_m[w] = m; s_l[w] = l; }
    __syncthreads();
    const float mg = fmaxf(fmaxf(s_m[0], s_m[1]), fmaxf(s_m[2], s_m[3]));
    const float f  = __expf(m - mg);   // wave-uniform
    f32x4* sc4 = (f32x4*)s_ctx[w];
    sc4[lane]       = c0 * f;
    sc4[lane + 64]  = c1 * f;
    sc4[lane + 128] = c2 * f;
    sc4[lane + 192] = c3 * f;
    __syncthreads();

    float lb = 0.f;
    #pragma unroll
    for (int i = 0; i < 4; ++i) lb += s_l[i] * __expf(s_m[i] - mg);

    float* pout = partials + (size_t)(b * NCHUNK + chunk) * PSTRIDE;
    const f32x4 v0 = ((const f32x4*)s_ctx[0])[tid];
    const f32x4 v1 = ((const f32x4*)s_ctx[1])[tid];
    const f32x4 v2 = ((const f32x4*)s_ctx[2])[tid];
    const f32x4 v3 = ((const f32x4*)s_ctx[3])[tid];
    const f32x4 sum = (v0 + v1) + (v2 + v3);
    ((f32x4*)pout)[tid] = sum;
    if (tid == 0) { pout[HID] = mg; pout[HID + 1] = lb; }
}

// -------- Pass 2: cross-chunk combine + weights normalization --------
// grid = BATCH * 8 blocks; each block redundantly recomputes the cheap
// (m,l) combine; sub-block 0 writes context, all 8 split the weights row.
template<int NCHUNK>
__global__ __launch_bounds__(256)
void attn_pass2(const float* __restrict__ partials,
                float* __restrict__ out_ctx,    // [B,H]
                float* __restrict__ weights)    // [B,S] in-place raw->softmax
{
    const int b   = blockIdx.x >> 3;
    const int sub = blockIdx.x & 7;
    const int tid = threadIdx.x;
    __shared__ float sm[NCHUNK], sl[NCHUNK];
    if (tid < NCHUNK) {
        const float* p = partials + (size_t)(b * NCHUNK + tid) * PSTRIDE;
        sm[tid] = p[HID];
        sl[tid] = p[HID + 1];
    }
    __syncthreads();

    float mg = -INFINITY;
    #pragma unroll
    for (int c = 0; c < NCHUNK; ++c) mg = fmaxf(mg, sm[c]);
    float lg = 0.f;
    #pragma unroll
    for (int c = 0; c < NCHUNK; ++c) lg += sl[c] * __expf(sm[c] - mg);
    const float inv = 1.f / lg;

    if (sub == 0) {
        // context: one float4 per thread (H = 1024 = 256 float4)
        f32x4 acc = (f32x4)(0.f);
        #pragma unroll 4
        for (int c = 0; c < NCHUNK; ++c) {
            const f32x4* p4 = (const f32x4*)(partials + (size_t)(b * NCHUNK + c) * PSTRIDE);
            const float fc = __expf(sm[c] - mg);
            acc += fc * p4[tid];
        }
        acc *= inv;
        ((f32x4*)(out_ctx + (size_t)b * HID))[tid] = acc;
    }

    // weights: normalize raw scores in place, SEQ/8 = 512 per sub-block
    float* wrow = weights + (size_t)b * SEQ;
    const int s0 = sub * (SEQ / 8);
    #pragma unroll
    for (int i = 0; i < SEQ / 8 / 256; ++i) {
        const int s = s0 + i * 256 + tid;
        wrow[s] = __expf(wrow[s] - mg) * inv;
    }
}

extern "C" void kernel_launch(void* const* d_in, const int* in_sizes, int n_in,
                              void* d_out, int out_size, void* d_ws, size_t ws_size,
                              hipStream_t stream) {
    const float* hidden = (const float*)d_in[0];          // [2, 32, 1024]
    const float* enc    = (const float*)d_in[1];          // [32, 4096, 1024]
    const float* dec    = hidden + (size_t)BATCH * HID;   // hidden[-1] -> [32, 1024]

    float* out     = (float*)d_out;
    float* ctx_out = out;                                 // [32, 1024]
    float* w_out   = out + (size_t)BATCH * HID;           // [32, 4096]
    float* partials = (float*)d_ws;

#define LAUNCH_NC(NC)                                                              \
    do {                                                                           \
        attn_fused_pass1<NC><<<BATCH * NC, 256, 0, stream>>>(enc, dec, w_out,      \
                                                             partials);            \
        attn_pass2<NC><<<BATCH * 8, 256, 0, stream>>>(partials, ctx_out, w_out);   \
    } while (0)

    const size_t per_chunk_bytes = (size_t)BATCH * PSTRIDE * sizeof(float);
    if      (ws_size >= 32 * per_chunk_bytes) LAUNCH_NC(32);
    else if (ws_size >= 16 * per_chunk_bytes) LAUNCH_NC(16);
    else if (ws_size >=  8 * per_chunk_bytes) LAUNCH_NC(8);
    else if (ws_size >=  4 * per_chunk_bytes) LAUNCH_NC(4);
    else if (ws_size >=  2 * per_chunk_bytes) LAUNCH_NC(2);
    else                                      LAUNCH_NC(1);
#undef LAUNCH_NC
}

// Round 9
// 91.597 us; speedup vs baseline: 1.1849x; 1.1849x over previous
//
#include <hip/hip_runtime.h>
#include <math.h>

static constexpr int BATCH = 32;
static constexpr int SEQ   = 4096;
static constexpr int HID   = 1024;
static constexpr int PSTRIDE = HID + 8;   // ctx[1024] + m + l (+pad, keeps 16B alignment)

typedef float f32x4 __attribute__((ext_vector_type(4)));   // native vector: OK for nontemporal builtins

// -------- Pass 1: fused scores + online-softmax context partials --------
// grid = BATCH*NCHUNK blocks (NCHUNK=32 -> 1024 = exactly 4 blocks/CU).
// R6 known-good core (97.5us): 2-row unroll, treed dots, interleaved shfl
// chains, nontemporal loads. R9 delta: WAVE-INTERLEAVED rows — wave w reads
// rows 8k+w and 8k+4+w, so the block's 4 waves sweep one contiguous 128 KB
// region in lockstep (1024 DRAM streams instead of 4096 -> page locality).
template<int NCHUNK>
__global__ __launch_bounds__(256, 4)
void attn_fused_pass1(const float* __restrict__ enc,
                      const float* __restrict__ dec,
                      float* __restrict__ raw_scores,   // [B,S] = weights region of d_out
                      float* __restrict__ partials)     // [B*NCHUNK][PSTRIDE]
{
    constexpr int RC    = SEQ / NCHUNK;   // rows per chunk (128 at NCHUNK=32)
    constexpr int NPAIR = RC / 8;         // row-pairs per wave (16 at NCHUNK=32)
    static_assert(RC % 8 == 0, "wave-interleaved 2-row unroll");
    const int b     = blockIdx.x / NCHUNK;
    const int chunk = blockIdx.x % NCHUNK;
    const int tid   = threadIdx.x;
    const int w     = tid >> 6;
    const int lane  = tid & 63;

    __shared__ float s_dec[HID];
    __shared__ float s_ctx[4][HID];
    __shared__ float s_m[4], s_l[4];

    // stage dec[b] (4 KB) then keep this lane's 16-float fragment in registers
    ((float4*)s_dec)[tid] = ((const float4*)(dec + (size_t)b * HID))[tid];
    __syncthreads();
    const f32x4* sd = (const f32x4*)s_dec;
    const f32x4 d0 = sd[lane], d1 = sd[lane + 64], d2 = sd[lane + 128], d3 = sd[lane + 192];

    float m = -INFINITY, l = 0.f;
    f32x4 c0 = (f32x4)(0.f);
    f32x4 c1 = c0, c2 = c0, c3 = c0;

    // block-contiguous base; this wave's rows are 8k+w (A) and 8k+4+w (B)
    const f32x4* base = (const f32x4*)(enc + ((size_t)b * SEQ + chunk * RC) * HID);
    float* sout = raw_scores + (size_t)b * SEQ + chunk * RC;

    for (int k = 0; k < NPAIR; ++k) {
        const int rowA = 8 * k + w;
        const f32x4* rpA = base + (size_t)rowA * (HID / 4);
        const f32x4* rpB = rpA + HID;          // +4 rows (4*HID/4 f32x4)
        const f32x4 a0 = __builtin_nontemporal_load(rpA + lane);
        const f32x4 a1 = __builtin_nontemporal_load(rpA + lane + 64);
        const f32x4 a2 = __builtin_nontemporal_load(rpA + lane + 128);
        const f32x4 a3 = __builtin_nontemporal_load(rpA + lane + 192);
        const f32x4 b0 = __builtin_nontemporal_load(rpB + lane);
        const f32x4 b1 = __builtin_nontemporal_load(rpB + lane + 64);
        const f32x4 b2 = __builtin_nontemporal_load(rpB + lane + 128);
        const f32x4 b3 = __builtin_nontemporal_load(rpB + lane + 192);

        // treed dot partials: 4 independent 4-FMA chains each, then 2 adds
        float tA0 = a0.x*d0.x + a0.y*d0.y + a0.z*d0.z + a0.w*d0.w;
        float tA1 = a1.x*d1.x + a1.y*d1.y + a1.z*d1.z + a1.w*d1.w;
        float tA2 = a2.x*d2.x + a2.y*d2.y + a2.z*d2.z + a2.w*d2.w;
        float tA3 = a3.x*d3.x + a3.y*d3.y + a3.z*d3.z + a3.w*d3.w;
        float tB0 = b0.x*d0.x + b0.y*d0.y + b0.z*d0.z + b0.w*d0.w;
        float tB1 = b1.x*d1.x + b1.y*d1.y + b1.z*d1.z + b1.w*d1.w;
        float tB2 = b2.x*d2.x + b2.y*d2.y + b2.z*d2.z + b2.w*d2.w;
        float tB3 = b3.x*d3.x + b3.y*d3.y + b3.z*d3.z + b3.w*d3.w;
        float tA = (tA0 + tA1) + (tA2 + tA3);
        float tB = (tB0 + tB1) + (tB2 + tB3);

        // two independent 6-step reduce chains, interleaved
        #pragma unroll
        for (int off = 32; off > 0; off >>= 1) {
            tA += __shfl_xor(tA, off, 64);
            tB += __shfl_xor(tB, off, 64);
        }

        if (lane == 0) {
            sout[rowA]     = tA;             // raw scores; normalized in pass 2
            sout[rowA + 4] = tB;
        }

        const float mn = fmaxf(m, fmaxf(tA, tB));
        if (mn > m) {                        // wave-uniform, rare after warm-up
            const float sc = __expf(m - mn); // m=-inf first time -> 0
            l *= sc;
            c0 *= sc; c1 *= sc; c2 *= sc; c3 *= sc;
            m = mn;
        }
        const float pA = __expf(tA - m);
        const float pB = __expf(tB - m);
        l += pA + pB;
        c0 += pA*a0 + pB*b0;
        c1 += pA*a1 + pB*b1;
        c2 += pA*a2 + pB*b2;
        c3 += pA*a3 + pB*b3;
    }

    // ---- combine the 4 waves of this block ----
    if (lane == 0) { s_m[w] = m; s_l[w] = l; }
    __syncthreads();
    const float mg = fmaxf(fmaxf(s_m[0], s_m[1]), fmaxf(s_m[2], s_m[3]));
    const float f  = __expf(m - mg);   // wave-uniform
    f32x4* sc4 = (f32x4*)s_ctx[w];
    sc4[lane]       = c0 * f;
    sc4[lane + 64]  = c1 * f;
    sc4[lane + 128] = c2 * f;
    sc4[lane + 192] = c3 * f;
    __syncthreads();

    float lb = 0.f;
    #pragma unroll
    for (int i = 0; i < 4; ++i) lb += s_l[i] * __expf(s_m[i] - mg);

    float* pout = partials + (size_t)(b * NCHUNK + chunk) * PSTRIDE;
    const f32x4 v0 = ((const f32x4*)s_ctx[0])[tid];
    const f32x4 v1 = ((const f32x4*)s_ctx[1])[tid];
    const f32x4 v2 = ((const f32x4*)s_ctx[2])[tid];
    const f32x4 v3 = ((const f32x4*)s_ctx[3])[tid];
    const f32x4 sum = (v0 + v1) + (v2 + v3);
    ((f32x4*)pout)[tid] = sum;
    if (tid == 0) { pout[HID] = mg; pout[HID + 1] = lb; }
}

// -------- Pass 2: cross-chunk combine + weights normalization --------
// grid = BATCH * 8 blocks; each block redundantly recomputes the cheap
// (m,l) combine; sub-block 0 writes context, all 8 split the weights row.
template<int NCHUNK>
__global__ __launch_bounds__(256)
void attn_pass2(const float* __restrict__ partials,
                float* __restrict__ out_ctx,    // [B,H]
                float* __restrict__ weights)    // [B,S] in-place raw->softmax
{
    const int b   = blockIdx.x >> 3;
    const int sub = blockIdx.x & 7;
    const int tid = threadIdx.x;
    __shared__ float sm[NCHUNK], sl[NCHUNK];
    if (tid < NCHUNK) {
        const float* p = partials + (size_t)(b * NCHUNK + tid) * PSTRIDE;
        sm[tid] = p[HID];
        sl[tid] = p[HID + 1];
    }
    __syncthreads();

    float mg = -INFINITY;
    #pragma unroll
    for (int c = 0; c < NCHUNK; ++c) mg = fmaxf(mg, sm[c]);
    float lg = 0.f;
    #pragma unroll
    for (int c = 0; c < NCHUNK; ++c) lg += sl[c] * __expf(sm[c] - mg);
    const float inv = 1.f / lg;

    if (sub == 0) {
        // context: one float4 per thread (H = 1024 = 256 float4)
        f32x4 acc = (f32x4)(0.f);
        #pragma unroll 4
        for (int c = 0; c < NCHUNK; ++c) {
            const f32x4* p4 = (const f32x4*)(partials + (size_t)(b * NCHUNK + c) * PSTRIDE);
            const float fc = __expf(sm[c] - mg);
            acc += fc * p4[tid];
        }
        acc *= inv;
        ((f32x4*)(out_ctx + (size_t)b * HID))[tid] = acc;
    }

    // weights: normalize raw scores in place, SEQ/8 = 512 per sub-block
    float* wrow = weights + (size_t)b * SEQ;
    const int s0 = sub * (SEQ / 8);
    #pragma unroll
    for (int i = 0; i < SEQ / 8 / 256; ++i) {
        const int s = s0 + i * 256 + tid;
        wrow[s] = __expf(wrow[s] - mg) * inv;
    }
}

extern "C" void kernel_launch(void* const* d_in, const int* in_sizes, int n_in,
                              void* d_out, int out_size, void* d_ws, size_t ws_size,
                              hipStream_t stream) {
    const float* hidden = (const float*)d_in[0];          // [2, 32, 1024]
    const float* enc    = (const float*)d_in[1];          // [32, 4096, 1024]
    const float* dec    = hidden + (size_t)BATCH * HID;   // hidden[-1] -> [32, 1024]

    float* out     = (float*)d_out;
    float* ctx_out = out;                                 // [32, 1024]
    float* w_out   = out + (size_t)BATCH * HID;           // [32, 4096]
    float* partials = (float*)d_ws;

#define LAUNCH_NC(NC)                                                              \
    do {                                                                           \
        attn_fused_pass1<NC><<<BATCH * NC, 256, 0, stream>>>(enc, dec, w_out,      \
                                                             partials);            \
        attn_pass2<NC><<<BATCH * 8, 256, 0, stream>>>(partials, ctx_out, w_out);   \
    } while (0)

    const size_t per_chunk_bytes = (size_t)BATCH * PSTRIDE * sizeof(float);
    if      (ws_size >= 32 * per_chunk_bytes) LAUNCH_NC(32);
    else if (ws_size >= 16 * per_chunk_bytes) LAUNCH_NC(16);
    else if (ws_size >=  8 * per_chunk_bytes) LAUNCH_NC(8);
    else if (ws_size >=  4 * per_chunk_bytes) LAUNCH_NC(4);
    else if (ws_size >=  2 * per_chunk_bytes) LAUNCH_NC(2);
    else                                      LAUNCH_NC(1);
#undef LAUNCH_NC
}

// Round 10
// 89.395 us; speedup vs baseline: 1.2141x; 1.0246x over previous
//
#include <hip/hip_runtime.h>
#include <math.h>

static constexpr int BATCH = 32;
static constexpr int SEQ   = 4096;
static constexpr int HID   = 1024;
static constexpr int PSTRIDE = HID + 8;   // ctx[1024] + m + l (+pad, keeps 16B alignment)

typedef float f32x4 __attribute__((ext_vector_type(4)));   // native vector: OK for nontemporal builtins

// -------- Pass 1: fused scores + online-softmax context partials --------
// R10: 512-thread blocks (8 waves), NCHUNK=16 -> 512 blocks. Identical
// occupancy (16 waves/CU: 2 blocks/CU x 8 waves) and per-wave code as R9,
// but each block sweeps a 1 MB contiguous region with 8 waves in lockstep
// (64 KB per block-iteration) -> 512 DRAM streams instead of 1024.
// Wave w reads rows 16k+w (A) and 16k+8+w (B).
template<int NCHUNK>
__global__ __launch_bounds__(512, 4)
void attn_fused_pass1(const float* __restrict__ enc,
                      const float* __restrict__ dec,
                      float* __restrict__ raw_scores,   // [B,S] = weights region of d_out
                      float* __restrict__ partials)     // [B*NCHUNK][PSTRIDE]
{
    constexpr int RC    = SEQ / NCHUNK;   // rows per chunk (256 at NCHUNK=16)
    constexpr int NPAIR = RC / 16;        // row-pairs per wave (16 at NCHUNK=16)
    static_assert(RC % 16 == 0, "8-wave interleaved 2-row unroll");
    const int b     = blockIdx.x / NCHUNK;
    const int chunk = blockIdx.x % NCHUNK;
    const int tid   = threadIdx.x;
    const int w     = tid >> 6;           // 0..7
    const int lane  = tid & 63;

    __shared__ float s_dec[HID];
    __shared__ float s_ctx[8][HID];
    __shared__ float s_m[8], s_l[8];

    // stage dec[b] (4 KB) then keep this lane's 16-float fragment in registers
    if (tid < HID / 4) ((float4*)s_dec)[tid] = ((const float4*)(dec + (size_t)b * HID))[tid];
    __syncthreads();
    const f32x4* sd = (const f32x4*)s_dec;
    const f32x4 d0 = sd[lane], d1 = sd[lane + 64], d2 = sd[lane + 128], d3 = sd[lane + 192];

    float m = -INFINITY, l = 0.f;
    f32x4 c0 = (f32x4)(0.f);
    f32x4 c1 = c0, c2 = c0, c3 = c0;

    // block-contiguous base; this wave's rows are 16k+w (A) and 16k+8+w (B)
    const f32x4* base = (const f32x4*)(enc + ((size_t)b * SEQ + chunk * RC) * HID);
    float* sout = raw_scores + (size_t)b * SEQ + chunk * RC;

    for (int k = 0; k < NPAIR; ++k) {
        const int rowA = 16 * k + w;
        const f32x4* rpA = base + (size_t)rowA * (HID / 4);
        const f32x4* rpB = rpA + 8 * (HID / 4);   // +8 rows
        const f32x4 a0 = __builtin_nontemporal_load(rpA + lane);
        const f32x4 a1 = __builtin_nontemporal_load(rpA + lane + 64);
        const f32x4 a2 = __builtin_nontemporal_load(rpA + lane + 128);
        const f32x4 a3 = __builtin_nontemporal_load(rpA + lane + 192);
        const f32x4 b0 = __builtin_nontemporal_load(rpB + lane);
        const f32x4 b1 = __builtin_nontemporal_load(rpB + lane + 64);
        const f32x4 b2 = __builtin_nontemporal_load(rpB + lane + 128);
        const f32x4 b3 = __builtin_nontemporal_load(rpB + lane + 192);

        // treed dot partials: 4 independent 4-FMA chains each, then 2 adds
        float tA0 = a0.x*d0.x + a0.y*d0.y + a0.z*d0.z + a0.w*d0.w;
        float tA1 = a1.x*d1.x + a1.y*d1.y + a1.z*d1.z + a1.w*d1.w;
        float tA2 = a2.x*d2.x + a2.y*d2.y + a2.z*d2.z + a2.w*d2.w;
        float tA3 = a3.x*d3.x + a3.y*d3.y + a3.z*d3.z + a3.w*d3.w;
        float tB0 = b0.x*d0.x + b0.y*d0.y + b0.z*d0.z + b0.w*d0.w;
        float tB1 = b1.x*d1.x + b1.y*d1.y + b1.z*d1.z + b1.w*d1.w;
        float tB2 = b2.x*d2.x + b2.y*d2.y + b2.z*d2.z + b2.w*d2.w;
        float tB3 = b3.x*d3.x + b3.y*d3.y + b3.z*d3.z + b3.w*d3.w;
        float tA = (tA0 + tA1) + (tA2 + tA3);
        float tB = (tB0 + tB1) + (tB2 + tB3);

        // two independent 6-step reduce chains, interleaved
        #pragma unroll
        for (int off = 32; off > 0; off >>= 1) {
            tA += __shfl_xor(tA, off, 64);
            tB += __shfl_xor(tB, off, 64);
        }

        if (lane == 0) {
            sout[rowA]     = tA;             // raw scores; normalized in pass 2
            sout[rowA + 8] = tB;
        }

        const float mn = fmaxf(m, fmaxf(tA, tB));
        if (mn > m) {                        // wave-uniform, rare after warm-up
            const float sc = __expf(m - mn); // m=-inf first time -> 0
            l *= sc;
            c0 *= sc; c1 *= sc; c2 *= sc; c3 *= sc;
            m = mn;
        }
        const float pA = __expf(tA - m);
        const float pB = __expf(tB - m);
        l += pA + pB;
        c0 += pA*a0 + pB*b0;
        c1 += pA*a1 + pB*b1;
        c2 += pA*a2 + pB*b2;
        c3 += pA*a3 + pB*b3;
    }

    // ---- combine the 8 waves of this block ----
    if (lane == 0) { s_m[w] = m; s_l[w] = l; }
    __syncthreads();
    const float mg = fmaxf(fmaxf(fmaxf(s_m[0], s_m[1]), fmaxf(s_m[2], s_m[3])),
                           fmaxf(fmaxf(s_m[4], s_m[5]), fmaxf(s_m[6], s_m[7])));
    const float f  = __expf(m - mg);   // wave-uniform
    f32x4* sc4 = (f32x4*)s_ctx[w];
    sc4[lane]       = c0 * f;
    sc4[lane + 64]  = c1 * f;
    sc4[lane + 128] = c2 * f;
    sc4[lane + 192] = c3 * f;
    __syncthreads();

    float* pout = partials + (size_t)(b * NCHUNK + chunk) * PSTRIDE;
    if (tid < HID / 4) {
        const f32x4 v0 = ((const f32x4*)s_ctx[0])[tid];
        const f32x4 v1 = ((const f32x4*)s_ctx[1])[tid];
        const f32x4 v2 = ((const f32x4*)s_ctx[2])[tid];
        const f32x4 v3 = ((const f32x4*)s_ctx[3])[tid];
        const f32x4 v4 = ((const f32x4*)s_ctx[4])[tid];
        const f32x4 v5 = ((const f32x4*)s_ctx[5])[tid];
        const f32x4 v6 = ((const f32x4*)s_ctx[6])[tid];
        const f32x4 v7 = ((const f32x4*)s_ctx[7])[tid];
        const f32x4 sum = ((v0 + v1) + (v2 + v3)) + ((v4 + v5) + (v6 + v7));
        ((f32x4*)pout)[tid] = sum;
    }
    if (tid == 0) {
        float lb = 0.f;
        #pragma unroll
        for (int i = 0; i < 8; ++i) lb += s_l[i] * __expf(s_m[i] - mg);
        pout[HID] = mg; pout[HID + 1] = lb;
    }
}

// -------- Pass 2: cross-chunk combine + weights normalization --------
// grid = BATCH * 8 blocks; each block redundantly recomputes the cheap
// (m,l) combine; sub-block 0 writes context, all 8 split the weights row.
template<int NCHUNK>
__global__ __launch_bounds__(256)
void attn_pass2(const float* __restrict__ partials,
                float* __restrict__ out_ctx,    // [B,H]
                float* __restrict__ weights)    // [B,S] in-place raw->softmax
{
    const int b   = blockIdx.x >> 3;
    const int sub = blockIdx.x & 7;
    const int tid = threadIdx.x;
    __shared__ float sm[NCHUNK], sl[NCHUNK];
    if (tid < NCHUNK) {
        const float* p = partials + (size_t)(b * NCHUNK + tid) * PSTRIDE;
        sm[tid] = p[HID];
        sl[tid] = p[HID + 1];
    }
    __syncthreads();

    float mg = -INFINITY;
    #pragma unroll
    for (int c = 0; c < NCHUNK; ++c) mg = fmaxf(mg, sm[c]);
    float lg = 0.f;
    #pragma unroll
    for (int c = 0; c < NCHUNK; ++c) lg += sl[c] * __expf(sm[c] - mg);
    const float inv = 1.f / lg;

    if (sub == 0) {
        // context: one float4 per thread (H = 1024 = 256 float4)
        f32x4 acc = (f32x4)(0.f);
        #pragma unroll 4
        for (int c = 0; c < NCHUNK; ++c) {
            const f32x4* p4 = (const f32x4*)(partials + (size_t)(b * NCHUNK + c) * PSTRIDE);
            const float fc = __expf(sm[c] - mg);
            acc += fc * p4[tid];
        }
        acc *= inv;
        ((f32x4*)(out_ctx + (size_t)b * HID))[tid] = acc;
    }

    // weights: normalize raw scores in place, SEQ/8 = 512 per sub-block
    float* wrow = weights + (size_t)b * SEQ;
    const int s0 = sub * (SEQ / 8);
    #pragma unroll
    for (int i = 0; i < SEQ / 8 / 256; ++i) {
        const int s = s0 + i * 256 + tid;
        wrow[s] = __expf(wrow[s] - mg) * inv;
    }
}

extern "C" void kernel_launch(void* const* d_in, const int* in_sizes, int n_in,
                              void* d_out, int out_size, void* d_ws, size_t ws_size,
                              hipStream_t stream) {
    const float* hidden = (const float*)d_in[0];          // [2, 32, 1024]
    const float* enc    = (const float*)d_in[1];          // [32, 4096, 1024]
    const float* dec    = hidden + (size_t)BATCH * HID;   // hidden[-1] -> [32, 1024]

    float* out     = (float*)d_out;
    float* ctx_out = out;                                 // [32, 1024]
    float* w_out   = out + (size_t)BATCH * HID;           // [32, 4096]
    float* partials = (float*)d_ws;

#define LAUNCH_NC(NC)                                                              \
    do {                                                                           \
        attn_fused_pass1<NC><<<BATCH * NC, 512, 0, stream>>>(enc, dec, w_out,      \
                                                             partials);            \
        attn_pass2<NC><<<BATCH * 8, 256, 0, stream>>>(partials, ctx_out, w_out);   \
    } while (0)

    const size_t per_chunk_bytes = (size_t)BATCH * PSTRIDE * sizeof(float);
    if      (ws_size >= 16 * per_chunk_bytes) LAUNCH_NC(16);
    else if (ws_size >=  8 * per_chunk_bytes) LAUNCH_NC(8);
    else if (ws_size >=  4 * per_chunk_bytes) LAUNCH_NC(4);
    else                                      LAUNCH_NC(2);
#undef LAUNCH_NC
}

// Round 11
// 88.416 us; speedup vs baseline: 1.2275x; 1.0111x over previous
//
#include <hip/hip_runtime.h>
#include <math.h>

static constexpr int BATCH = 32;
static constexpr int SEQ   = 4096;
static constexpr int HID   = 1024;
static constexpr int PSTRIDE = HID + 8;   // ctx[1024] + m + l (+pad, keeps 16B alignment)

typedef float f32x4 __attribute__((ext_vector_type(4)));   // native vector: OK for nontemporal builtins

// -------- Pass 1: fused scores + online-softmax context partials --------
// R11: 1024-thread blocks (16 waves), NCHUNK=8 -> 256 blocks = exactly
// 1 block/CU (perfect balance), occupancy unchanged at 16 waves/CU.
// Each block sweeps a 2 MB contiguous region with 16 waves in lockstep
// (128 KB per block-iteration) -> 256 DRAM streams (one per CU), the
// minimum for this structure. Wave w reads rows 32k+w (A) and 32k+16+w (B).
template<int NCHUNK>
__global__ __launch_bounds__(1024, 4)
void attn_fused_pass1(const float* __restrict__ enc,
                      const float* __restrict__ dec,
                      float* __restrict__ raw_scores,   // [B,S] = weights region of d_out
                      float* __restrict__ partials)     // [B*NCHUNK][PSTRIDE]
{
    constexpr int RC    = SEQ / NCHUNK;   // rows per chunk (512 at NCHUNK=8)
    constexpr int NPAIR = RC / 32;        // row-pairs per wave (16 at NCHUNK=8)
    static_assert(RC % 32 == 0, "16-wave interleaved 2-row unroll");
    const int b     = blockIdx.x / NCHUNK;
    const int chunk = blockIdx.x % NCHUNK;
    const int tid   = threadIdx.x;
    const int w     = tid >> 6;           // 0..15
    const int lane  = tid & 63;

    __shared__ float s_dec[HID];
    __shared__ float s_ctx[16][HID];
    __shared__ float s_m[16], s_l[16];

    // stage dec[b] (4 KB) then keep this lane's 16-float fragment in registers
    if (tid < HID / 4) ((float4*)s_dec)[tid] = ((const float4*)(dec + (size_t)b * HID))[tid];
    __syncthreads();
    const f32x4* sd = (const f32x4*)s_dec;
    const f32x4 d0 = sd[lane], d1 = sd[lane + 64], d2 = sd[lane + 128], d3 = sd[lane + 192];

    float m = -INFINITY, l = 0.f;
    f32x4 c0 = (f32x4)(0.f);
    f32x4 c1 = c0, c2 = c0, c3 = c0;

    // block-contiguous base; this wave's rows are 32k+w (A) and 32k+16+w (B)
    const f32x4* base = (const f32x4*)(enc + ((size_t)b * SEQ + chunk * RC) * HID);
    float* sout = raw_scores + (size_t)b * SEQ + chunk * RC;

    for (int k = 0; k < NPAIR; ++k) {
        const int rowA = 32 * k + w;
        const f32x4* rpA = base + (size_t)rowA * (HID / 4);
        const f32x4* rpB = rpA + 16 * (HID / 4);   // +16 rows
        const f32x4 a0 = __builtin_nontemporal_load(rpA + lane);
        const f32x4 a1 = __builtin_nontemporal_load(rpA + lane + 64);
        const f32x4 a2 = __builtin_nontemporal_load(rpA + lane + 128);
        const f32x4 a3 = __builtin_nontemporal_load(rpA + lane + 192);
        const f32x4 b0 = __builtin_nontemporal_load(rpB + lane);
        const f32x4 b1 = __builtin_nontemporal_load(rpB + lane + 64);
        const f32x4 b2 = __builtin_nontemporal_load(rpB + lane + 128);
        const f32x4 b3 = __builtin_nontemporal_load(rpB + lane + 192);

        // treed dot partials: 4 independent 4-FMA chains each, then 2 adds
        float tA0 = a0.x*d0.x + a0.y*d0.y + a0.z*d0.z + a0.w*d0.w;
        float tA1 = a1.x*d1.x + a1.y*d1.y + a1.z*d1.z + a1.w*d1.w;
        float tA2 = a2.x*d2.x + a2.y*d2.y + a2.z*d2.z + a2.w*d2.w;
        float tA3 = a3.x*d3.x + a3.y*d3.y + a3.z*d3.z + a3.w*d3.w;
        float tB0 = b0.x*d0.x + b0.y*d0.y + b0.z*d0.z + b0.w*d0.w;
        float tB1 = b1.x*d1.x + b1.y*d1.y + b1.z*d1.z + b1.w*d1.w;
        float tB2 = b2.x*d2.x + b2.y*d2.y + b2.z*d2.z + b2.w*d2.w;
        float tB3 = b3.x*d3.x + b3.y*d3.y + b3.z*d3.z + b3.w*d3.w;
        float tA = (tA0 + tA1) + (tA2 + tA3);
        float tB = (tB0 + tB1) + (tB2 + tB3);

        // two independent 6-step reduce chains, interleaved
        #pragma unroll
        for (int off = 32; off > 0; off >>= 1) {
            tA += __shfl_xor(tA, off, 64);
            tB += __shfl_xor(tB, off, 64);
        }

        if (lane == 0) {
            sout[rowA]      = tA;            // raw scores; normalized in pass 2
            sout[rowA + 16] = tB;
        }

        const float mn = fmaxf(m, fmaxf(tA, tB));
        if (mn > m) {                        // wave-uniform, rare after warm-up
            const float sc = __expf(m - mn); // m=-inf first time -> 0
            l *= sc;
            c0 *= sc; c1 *= sc; c2 *= sc; c3 *= sc;
            m = mn;
        }
        const float pA = __expf(tA - m);
        const float pB = __expf(tB - m);
        l += pA + pB;
        c0 += pA*a0 + pB*b0;
        c1 += pA*a1 + pB*b1;
        c2 += pA*a2 + pB*b2;
        c3 += pA*a3 + pB*b3;
    }

    // ---- combine the 16 waves of this block ----
    if (lane == 0) { s_m[w] = m; s_l[w] = l; }
    __syncthreads();
    float mg = -INFINITY;
    #pragma unroll
    for (int i = 0; i < 16; ++i) mg = fmaxf(mg, s_m[i]);
    const float f = __expf(m - mg);   // wave-uniform
    f32x4* sc4 = (f32x4*)s_ctx[w];
    sc4[lane]       = c0 * f;
    sc4[lane + 64]  = c1 * f;
    sc4[lane + 128] = c2 * f;
    sc4[lane + 192] = c3 * f;
    __syncthreads();

    float* pout = partials + (size_t)(b * NCHUNK + chunk) * PSTRIDE;
    if (tid < HID / 4) {
        f32x4 sum = (f32x4)(0.f);
        #pragma unroll
        for (int i = 0; i < 16; ++i) sum += ((const f32x4*)s_ctx[i])[tid];
        ((f32x4*)pout)[tid] = sum;
    }
    if (tid == 0) {
        float lb = 0.f;
        #pragma unroll
        for (int i = 0; i < 16; ++i) lb += s_l[i] * __expf(s_m[i] - mg);
        pout[HID] = mg; pout[HID + 1] = lb;
    }
}

// -------- Pass 2: cross-chunk combine + weights normalization --------
// grid = BATCH * 8 blocks; each block redundantly recomputes the cheap
// (m,l) combine; sub-block 0 writes context, all 8 split the weights row.
template<int NCHUNK>
__global__ __launch_bounds__(256)
void attn_pass2(const float* __restrict__ partials,
                float* __restrict__ out_ctx,    // [B,H]
                float* __restrict__ weights)    // [B,S] in-place raw->softmax
{
    const int b   = blockIdx.x >> 3;
    const int sub = blockIdx.x & 7;
    const int tid = threadIdx.x;
    __shared__ float sm[NCHUNK], sl[NCHUNK];
    if (tid < NCHUNK) {
        const float* p = partials + (size_t)(b * NCHUNK + tid) * PSTRIDE;
        sm[tid] = p[HID];
        sl[tid] = p[HID + 1];
    }
    __syncthreads();

    float mg = -INFINITY;
    #pragma unroll
    for (int c = 0; c < NCHUNK; ++c) mg = fmaxf(mg, sm[c]);
    float lg = 0.f;
    #pragma unroll
    for (int c = 0; c < NCHUNK; ++c) lg += sl[c] * __expf(sm[c] - mg);
    const float inv = 1.f / lg;

    if (sub == 0) {
        // context: one float4 per thread (H = 1024 = 256 float4)
        f32x4 acc = (f32x4)(0.f);
        #pragma unroll
        for (int c = 0; c < NCHUNK; ++c) {
            const f32x4* p4 = (const f32x4*)(partials + (size_t)(b * NCHUNK + c) * PSTRIDE);
            const float fc = __expf(sm[c] - mg);
            acc += fc * p4[tid];
        }
        acc *= inv;
        ((f32x4*)(out_ctx + (size_t)b * HID))[tid] = acc;
    }

    // weights: normalize raw scores in place, SEQ/8 = 512 per sub-block
    float* wrow = weights + (size_t)b * SEQ;
    const int s0 = sub * (SEQ / 8);
    #pragma unroll
    for (int i = 0; i < SEQ / 8 / 256; ++i) {
        const int s = s0 + i * 256 + tid;
        wrow[s] = __expf(wrow[s] - mg) * inv;
    }
}

extern "C" void kernel_launch(void* const* d_in, const int* in_sizes, int n_in,
                              void* d_out, int out_size, void* d_ws, size_t ws_size,
                              hipStream_t stream) {
    const float* hidden = (const float*)d_in[0];          // [2, 32, 1024]
    const float* enc    = (const float*)d_in[1];          // [32, 4096, 1024]
    const float* dec    = hidden + (size_t)BATCH * HID;   // hidden[-1] -> [32, 1024]

    float* out     = (float*)d_out;
    float* ctx_out = out;                                 // [32, 1024]
    float* w_out   = out + (size_t)BATCH * HID;           // [32, 4096]
    float* partials = (float*)d_ws;

#define LAUNCH_NC(NC)                                                              \
    do {                                                                           \
        attn_fused_pass1<NC><<<BATCH * NC, 1024, 0, stream>>>(enc, dec, w_out,     \
                                                              partials);           \
        attn_pass2<NC><<<BATCH * 8, 256, 0, stream>>>(partials, ctx_out, w_out);   \
    } while (0)

    const size_t per_chunk_bytes = (size_t)BATCH * PSTRIDE * sizeof(float);
    if      (ws_size >= 8 * per_chunk_bytes) LAUNCH_NC(8);
    else if (ws_size >= 4 * per_chunk_bytes) LAUNCH_NC(4);
    else                                     LAUNCH_NC(2);
#undef LAUNCH_NC
}